// Round 3
// baseline (195.776 us; speedup 1.0000x reference)
//
#include <hip/hip_runtime.h>

#define H 1024
#define W 1024
#define NB 8
#define TY 8
#define NT 256

__global__ void ncc_zero(double* acc) { *acc = 0.0; }

__global__ void ncc_finalize(const double* __restrict__ acc, float* __restrict__ out) {
    out[0] = 1.0f - (float)(*acc * (1.0 / 8388608.0));  // 8*1024*1024 pixels
}

// Load 12 cols (x0-4 .. x0+7) of row r from base, clamped addresses + zero-masked halo.
__device__ __forceinline__ void load_row12(const float* __restrict__ p,
                                           int xlo, int x0, int xhi,
                                           float mlo, float mhi, float* f) {
    float4 lo = *(const float4*)(p + xlo);
    float4 md = *(const float4*)(p + x0);
    float4 hi = *(const float4*)(p + xhi);
    f[0] = lo.x * mlo; f[1] = lo.y * mlo; f[2]  = lo.z * mlo; f[3]  = lo.w * mlo;
    f[4] = md.x;       f[5] = md.y;       f[6]  = md.z;       f[7]  = md.w;
    f[8] = hi.x * mhi; f[9] = hi.y * mhi; f[10] = hi.z * mhi; f[11] = hi.w * mhi;
}

template <bool ADD>
__device__ __forceinline__ void accum12(float* vI, float* vJ, float* vII, float* vJJ, float* vIJ,
                                        const float* fi, const float* fj) {
    #pragma unroll
    for (int c = 0; c < 12; ++c) {
        const float pii = fi[c] * fi[c];
        const float pjj = fj[c] * fj[c];
        const float pij = fi[c] * fj[c];
        if (ADD) {
            vI[c] += fi[c]; vJ[c] += fj[c]; vII[c] += pii; vJJ[c] += pjj; vIJ[c] += pij;
        } else {
            vI[c] -= fi[c]; vJ[c] -= fj[c]; vII[c] -= pii; vJJ[c] -= pjj; vIJ[c] -= pij;
        }
    }
}

// 9-tap sliding horizontal sums: out[c] = sum(v[c..c+8]), c = 0..3
__device__ __forceinline__ void hpass(const float* v, float* o) {
    float s = v[0] + v[1] + v[2] + v[3] + v[4] + v[5] + v[6] + v[7] + v[8];
    o[0] = s; s += v[9]  - v[0];
    o[1] = s; s += v[10] - v[1];
    o[2] = s; s += v[11] - v[2];
    o[3] = s;
}

__global__ __launch_bounds__(NT, 4) void ncc_main(
    const float* __restrict__ Jg,  // y_pred
    const float* __restrict__ Ig,  // y_true
    double* __restrict__ acc)
{
    const int b  = blockIdx.x;
    const int y0 = blockIdx.y * TY;
    const int t  = threadIdx.x;
    const int x0 = t << 2;                       // 4 output cols per thread; block spans W

    const int   xlo = max(x0 - 4, 0);            // clamped halo addresses (float4-aligned)
    const int   xhi = min(x0 + 4, W - 4);
    const float mlo = (x0 >= 4)     ? 1.0f : 0.0f;
    const float mhi = (x0 <= W - 8) ? 1.0f : 0.0f;

    const float* __restrict__ Ib = Ig + (size_t)b * (H * W);
    const float* __restrict__ Jb = Jg + (size_t)b * (H * W);

    // vertical running window sums over rows, for 12 columns
    float vI[12], vJ[12], vII[12], vJJ[12], vIJ[12];
    #pragma unroll
    for (int c = 0; c < 12; ++c) { vI[c] = vJ[c] = vII[c] = vJJ[c] = vIJ[c] = 0.0f; }

    // initial window: rows y0-4 .. y0+4 (zero-padded outside image)
    for (int r = y0 - 4; r <= y0 + 4; ++r) {
        if ((unsigned)r < (unsigned)H) {
            float fi[12], fj[12];
            load_row12(Ib + (size_t)r * W, xlo, x0, xhi, mlo, mhi, fi);
            load_row12(Jb + (size_t)r * W, xlo, x0, xhi, mlo, mhi, fj);
            accum12<true>(vI, vJ, vII, vJJ, vIJ, fi, fj);
        }
    }

    const float inv = 1.0f / 81.0f;
    float accv = 0.0f;

    for (int y = y0; y < y0 + TY; ++y) {
        const int ra = y + 5;   // row entering the window
        const int rs = y - 4;   // row leaving the window

        // 1) issue all slide loads up front (batched, overlap with compute below)
        float fia[12], fja[12], fis[12], fjs[12];
        const bool va = (ra < H);
        const bool vs = (rs >= 0);
        if (va) {
            load_row12(Ib + (size_t)ra * W, xlo, x0, xhi, mlo, mhi, fia);
            load_row12(Jb + (size_t)ra * W, xlo, x0, xhi, mlo, mhi, fja);
        }
        if (vs) {
            load_row12(Ib + (size_t)rs * W, xlo, x0, xhi, mlo, mhi, fis);
            load_row12(Jb + (size_t)rs * W, xlo, x0, xhi, mlo, mhi, fjs);
        }

        // 2) horizontal 9-tap sums + per-pixel cc for current row y
        float hI[4], hJ[4], hII[4], hJJ[4], hIJ[4];
        hpass(vI,  hI);
        hpass(vJ,  hJ);
        hpass(vII, hII);
        hpass(vJJ, hJJ);
        hpass(vIJ, hIJ);

        #pragma unroll
        for (int c = 0; c < 4; ++c) {
            const float uI    = hI[c] * inv;
            const float uJ    = hJ[c] * inv;
            const float cross = hIJ[c] * inv - uI * uJ;
            const float Iv    = hII[c] * inv - uI * uI;
            const float Jv    = hJJ[c] * inv - uJ * uJ;
            accv += cross * rsqrtf(fmaxf(Iv * Jv, 1e-7f));
        }

        // 3) apply the slide
        if (va) accum12<true >(vI, vJ, vII, vJJ, vIJ, fia, fja);
        if (vs) accum12<false>(vI, vJ, vII, vJJ, vIJ, fis, fjs);
    }

    // wave reduction (64 lanes), one double atomic per wave
    #pragma unroll
    for (int off = 32; off > 0; off >>= 1)
        accv += __shfl_down(accv, off);
    if ((t & 63) == 0)
        atomicAdd(acc, (double)accv);
}

extern "C" void kernel_launch(void* const* d_in, const int* in_sizes, int n_in,
                              void* d_out, int out_size, void* d_ws, size_t ws_size,
                              hipStream_t stream) {
    const float* y_pred = (const float*)d_in[0];  // Ji
    const float* y_true = (const float*)d_in[1];  // Ii
    float* out = (float*)d_out;
    double* accp = (double*)d_ws;

    ncc_zero<<<dim3(1), dim3(1), 0, stream>>>(accp);
    dim3 grid(NB, H / TY);  // 8 x 128 = 1024 blocks, 4 waves each; no barriers, no LDS
    ncc_main<<<grid, dim3(NT), 0, stream>>>(y_pred, y_true, accp);
    ncc_finalize<<<dim3(1), dim3(1), 0, stream>>>(accp, out);
}